// Round 2
// baseline (246.664 us; speedup 1.0000x reference)
//
#include <hip/hip_runtime.h>

// db2 coefficients (standard Daubechies-2, matches reference construction)
constexpr float h0 = 0.48296291314469025f;  // (1+√3)/(4√2)
constexpr float h1 = 0.83651630373746900f;  // (3+√3)/(4√2)
constexpr float h2 = 0.22414386804185735f;  // (3-√3)/(4√2)
constexpr float h3 = -0.12940952255092145f; // (1-√3)/(4√2)

// lpf = [h3,h2,h1,h0]; hpf = [-h0,h1,-h2,h3]
// Output row r = 2m+er taps orig rows m, min(m+1,511).
//   lpf vertical: er=0 -> (h2, h0); er=1 -> (h3, h1)
//   hpf vertical: er=0 -> (h1, h3); er=1 -> (-h0, -h2)
// Channels: c0,c1 = (lpf,lpf) [LH replicates source bug -> pre-summed A=x+y];
// c2 = (lpf_h, hpf_w); c3 = (hpf_h, hpf_w); c2,c3 share horizontal hpf.
//
// V3: V2 (R=4 vertical register-blocking + XCD swizzle) + forced up-front
// loads. V2's lesson: the compiler re-scheduled the 15 loads into a
// load-3/wait/compute stream (VGPR_Count=32) -> MLP dropped 6->3 and the
// kernel became latency-bound (92 us, ~3 TB/s). The asm memory barrier
// below pins all 15 loads before any compute (MLP=15/thread), at the cost
// of ~80 VGPRs (still 6 waves/SIMD).

constexpr int R = 4;  // input rows per thread

__global__ __launch_bounds__(256) void idwt_kernel(const float4* __restrict__ x,
                                                   float4* __restrict__ out) {
    // XCD-aware bijective swizzle: grid = 4096 blocks, 8 XCDs, 4096 % 8 == 0.
    // XCD k executes logical ids [k*512, (k+1)*512) in order -> adjacent
    // row-strips share their boundary row within one XCD's L2.
    const int bid   = blockIdx.x;
    const int chunk = gridDim.x >> 3;               // 4096/8 = 512
    const int lid   = (bid & 7) * chunk + (bid >> 3);

    const int np = threadIdx.x;                      // 0..255 column-pair
    const int t  = lid & 127;                        // row-strip within image
    const int b  = lid >> 7;                         // batch

    const int n0 = np << 1;
    const int n2 = (n0 + 2 < 512) ? n0 + 2 : 511;    // clamp only at np==255
    const int m0 = t << 2;                           // first input row of strip

    const size_t base = (size_t)b * (512 * 512);

    // Load R+1 rows x 3 cols; the barrier after the loop prevents the
    // compiler from sinking any load below the first compute, so all 15
    // requests are in flight together (the whole point of this version).
    float4 p[R + 1][3];
#pragma unroll
    for (int r = 0; r <= R; ++r) {
        int mm = m0 + r;
        mm = (mm < 512) ? mm : 511;                  // symmetric-pad clamp (last strip only)
        const size_t row = base + (size_t)mm * 512;
        p[r][0] = x[row + n0];
        p[r][1] = x[row + n0 + 1];
        p[r][2] = x[row + n2];
    }
    asm volatile("" ::: "memory");   // MLP fence: issue all loads first

    // Per-row channel state: A = c0+c1 (both take the lpf/lpf path), z = c2, w = c3.
    float A[R + 1][3], z[R + 1][3], w[R + 1][3];
#pragma unroll
    for (int r = 0; r <= R; ++r) {
#pragma unroll
        for (int j = 0; j < 3; ++j) {
            A[r][j] = p[r][j].x + p[r][j].y;
            z[r][j] = p[r][j].z;
            w[r][j] = p[r][j].w;
        }
    }

    // out: [B, 1024, 1024] fp32 = rows of 256 float4; this thread owns
    // output rows 2*m0 .. 2*m0+7, float4-col np.
    size_t o = (size_t)((b << 10) + (m0 << 1)) * 256 + np;

#pragma unroll
    for (int r = 0; r < R; ++r) {
        float Lv0[3], Lv1[3], Hv0[3], Hv1[3];
#pragma unroll
        for (int j = 0; j < 3; ++j) {
            Lv0[j] = h2 * A[r][j] + h0 * A[r + 1][j];
            Lv1[j] = h3 * A[r][j] + h1 * A[r + 1][j];
            Hv0[j] = (h2 * z[r][j] + h0 * z[r + 1][j]) + (h1 * w[r][j] + h3 * w[r + 1][j]);
            Hv1[j] = (h3 * z[r][j] + h1 * z[r + 1][j]) + (-h0 * w[r][j] - h2 * w[r + 1][j]);
        }

        // horizontal: lpf ec=0 (h2,h0), ec=1 (h3,h1); hpf ec=0 (h1,h3), ec=1 (-h0,-h2)
        float4 r0, r1;
        r0.x = h2 * Lv0[0] + h0 * Lv0[1] + h1 * Hv0[0] + h3 * Hv0[1];
        r0.y = h3 * Lv0[0] + h1 * Lv0[1] - h0 * Hv0[0] - h2 * Hv0[1];
        r0.z = h2 * Lv0[1] + h0 * Lv0[2] + h1 * Hv0[1] + h3 * Hv0[2];
        r0.w = h3 * Lv0[1] + h1 * Lv0[2] - h0 * Hv0[1] - h2 * Hv0[2];
        r1.x = h2 * Lv1[0] + h0 * Lv1[1] + h1 * Hv1[0] + h3 * Hv1[1];
        r1.y = h3 * Lv1[0] + h1 * Lv1[1] - h0 * Hv1[0] - h2 * Hv1[1];
        r1.z = h2 * Lv1[1] + h0 * Lv1[2] + h1 * Hv1[1] + h3 * Hv1[2];
        r1.w = h3 * Lv1[1] + h1 * Lv1[2] - h0 * Hv1[1] - h2 * Hv1[2];

        out[o]       = r0;
        out[o + 256] = r1;
        o += 512;
    }
}

extern "C" void kernel_launch(void* const* d_in, const int* in_sizes, int n_in,
                              void* d_out, int out_size, void* d_ws, size_t ws_size,
                              hipStream_t stream) {
    const float4* x = (const float4*)d_in[0];
    float4* out = (float4*)d_out;
    // one thread per (b, 4-row strip, column-pair): 32 * 128 * 256 threads
    const int blocks = 32 * 128;   // 4096, divisible by 8 (bijective XCD swizzle)
    idwt_kernel<<<blocks, 256, 0, stream>>>(x, out);
}

// Round 3
// 241.835 us; speedup vs baseline: 1.0200x; 1.0200x over previous
//
#include <hip/hip_runtime.h>

// db2 coefficients (standard Daubechies-2, matches reference construction)
constexpr float h0 = 0.48296291314469025f;  // (1+√3)/(4√2)
constexpr float h1 = 0.83651630373746900f;  // (3+√3)/(4√2)
constexpr float h2 = 0.22414386804185735f;  // (3-√3)/(4√2)
constexpr float h3 = -0.12940952255092145f; // (1-√3)/(4√2)

// lpf = [h3,h2,h1,h0]; hpf = [-h0,h1,-h2,h3]
// Output row r = 2m+er taps orig rows m, min(m+1,511).
//   lpf vertical: er=0 -> (h2, h0); er=1 -> (h3, h1)
//   hpf vertical: er=0 -> (h1, h3); er=1 -> (-h0, -h2)
// Channels: c0,c1 = (lpf,lpf) [LH replicates source bug -> pre-summed A=x+y];
// c2 = (lpf_h, hpf_w); c3 = (hpf_h, hpf_w); c2,c3 share horizontal hpf.
//
// V4: V3 + REGISTER-LIVENESS pins on every loaded value.
// V3 post-mortem: an ordering-only asm barrier left VGPR_Count=32 -> the
// compiler kept its load-3/vmcnt(0)/consume serialized schedule and the
// kernel sat latency-bound at 2.3 TB/s. The per-value "v" pins below force
// all 15 float4 results live at one program point: all 15 loads must issue
// before the first pin's wait, giving graduated vmcnt(N) drains and
// 15-deep per-thread MLP. Cost: ~60 data VGPRs (expect ~100 total,
// 4-5 waves/SIMD -- fine for streaming).

constexpr int R = 4;  // input rows per thread

#define PIN4(v) asm volatile("" :: "v"((v).x), "v"((v).y), "v"((v).z), "v"((v).w))

__global__ __launch_bounds__(256) void idwt_kernel(const float4* __restrict__ x,
                                                   float4* __restrict__ out) {
    // XCD-aware bijective swizzle: grid = 4096 blocks, 8 XCDs, 4096 % 8 == 0.
    // XCD k executes logical ids [k*512, (k+1)*512) in order -> adjacent
    // row-strips share their boundary row within one XCD's L2.
    const int bid   = blockIdx.x;
    const int chunk = gridDim.x >> 3;               // 4096/8 = 512
    const int lid   = (bid & 7) * chunk + (bid >> 3);

    const int np = threadIdx.x;                      // 0..255 column-pair
    const int t  = lid & 127;                        // row-strip within image
    const int b  = lid >> 7;                         // batch

    const int n0 = np << 1;
    const int n2 = (n0 + 2 < 512) ? n0 + 2 : 511;    // clamp only at np==255
    const int m0 = t << 2;                           // first input row of strip

    const size_t base = (size_t)b * (512 * 512);

    // Issue all (R+1)*3 = 15 loads, then pin every result live.
    float4 p[R + 1][3];
#pragma unroll
    for (int r = 0; r <= R; ++r) {
        int mm = m0 + r;
        mm = (mm < 512) ? mm : 511;                  // symmetric-pad clamp (last strip only)
        const size_t row = base + (size_t)mm * 512;
        p[r][0] = x[row + n0];
        p[r][1] = x[row + n0 + 1];
        p[r][2] = x[row + n2];
    }
#pragma unroll
    for (int r = 0; r <= R; ++r) {
        PIN4(p[r][0]); PIN4(p[r][1]); PIN4(p[r][2]);
    }

    // Per-row channel state: A = c0+c1 (both take the lpf/lpf path), z = c2, w = c3.
    float A[R + 1][3], z[R + 1][3], w[R + 1][3];
#pragma unroll
    for (int r = 0; r <= R; ++r) {
#pragma unroll
        for (int j = 0; j < 3; ++j) {
            A[r][j] = p[r][j].x + p[r][j].y;
            z[r][j] = p[r][j].z;
            w[r][j] = p[r][j].w;
        }
    }

    // out: [B, 1024, 1024] fp32 = rows of 256 float4; this thread owns
    // output rows 2*m0 .. 2*m0+7, float4-col np.
    size_t o = (size_t)((b << 10) + (m0 << 1)) * 256 + np;

#pragma unroll
    for (int r = 0; r < R; ++r) {
        float Lv0[3], Lv1[3], Hv0[3], Hv1[3];
#pragma unroll
        for (int j = 0; j < 3; ++j) {
            Lv0[j] = h2 * A[r][j] + h0 * A[r + 1][j];
            Lv1[j] = h3 * A[r][j] + h1 * A[r + 1][j];
            Hv0[j] = (h2 * z[r][j] + h0 * z[r + 1][j]) + (h1 * w[r][j] + h3 * w[r + 1][j]);
            Hv1[j] = (h3 * z[r][j] + h1 * z[r + 1][j]) + (-h0 * w[r][j] - h2 * w[r + 1][j]);
        }

        // horizontal: lpf ec=0 (h2,h0), ec=1 (h3,h1); hpf ec=0 (h1,h3), ec=1 (-h0,-h2)
        float4 r0, r1;
        r0.x = h2 * Lv0[0] + h0 * Lv0[1] + h1 * Hv0[0] + h3 * Hv0[1];
        r0.y = h3 * Lv0[0] + h1 * Lv0[1] - h0 * Hv0[0] - h2 * Hv0[1];
        r0.z = h2 * Lv0[1] + h0 * Lv0[2] + h1 * Hv0[1] + h3 * Hv0[2];
        r0.w = h3 * Lv0[1] + h1 * Lv0[2] - h0 * Hv0[1] - h2 * Hv0[2];
        r1.x = h2 * Lv1[0] + h0 * Lv1[1] + h1 * Hv1[0] + h3 * Hv1[1];
        r1.y = h3 * Lv1[0] + h1 * Lv1[1] - h0 * Hv1[0] - h2 * Hv1[1];
        r1.z = h2 * Lv1[1] + h0 * Lv1[2] + h1 * Hv1[1] + h3 * Hv1[2];
        r1.w = h3 * Lv1[1] + h1 * Lv1[2] - h0 * Hv1[1] - h2 * Hv1[2];

        out[o]       = r0;
        out[o + 256] = r1;
        o += 512;
    }
}

extern "C" void kernel_launch(void* const* d_in, const int* in_sizes, int n_in,
                              void* d_out, int out_size, void* d_ws, size_t ws_size,
                              hipStream_t stream) {
    const float4* x = (const float4*)d_in[0];
    float4* out = (float4*)d_out;
    // one thread per (b, 4-row strip, column-pair): 32 * 128 * 256 threads
    const int blocks = 32 * 128;   // 4096, divisible by 8 (bijective XCD swizzle)
    idwt_kernel<<<blocks, 256, 0, stream>>>(x, out);
}

// Round 5
// 229.653 us; speedup vs baseline: 1.0741x; 1.0530x over previous
//
#include <hip/hip_runtime.h>

// db2 coefficients (standard Daubechies-2, matches reference construction)
constexpr float h0 = 0.48296291314469025f;  // (1+√3)/(4√2)
constexpr float h1 = 0.83651630373746900f;  // (3+√3)/(4√2)
constexpr float h2 = 0.22414386804185735f;  // (3-√3)/(4√2)
constexpr float h3 = -0.12940952255092145f; // (1-√3)/(4√2)

// lpf = [h3,h2,h1,h0]; hpf = [-h0,h1,-h2,h3]
// Output row r = 2m+er taps orig rows m, min(m+1,511).
//   lpf vertical: er=0 -> (h2, h0); er=1 -> (h3, h1)
//   hpf vertical: er=0 -> (h1, h3); er=1 -> (-h0, -h2)
// Channels: c0,c1 = (lpf,lpf) [LH replicates source bug -> pre-summed];
// c2 = (lpf_h, hpf_w); c3 = (hpf_h, hpf_w); c2,c3 share horizontal hpf.
//
// V5b: V5 with the nontemporal-store compile fix (builtin requires a NATIVE
// vector type, not HIP's float4 class -> go through ext_vector_type(4)).
// Structure: V1 shape (one thread = one row-pair x column-pair, 2M threads,
// 6 loads, VGPR~32, TLP-maximal; V2-V4 showed ILP-forcing loses to TLP here)
// + (1) bijective XCD swizzle (boundary-row re-read becomes same-XCD L2 hit)
// + (2) non-temporal output stores (write-once stream stays out of L2/L3).

typedef float nfloat4 __attribute__((ext_vector_type(4)));  // native vec for builtin

__global__ __launch_bounds__(256) void idwt_kernel(const float4* __restrict__ x,
                                                   float4* __restrict__ out) {
    // XCD-aware bijective swizzle: 8192 blocks, 8 XCDs, 8192 % 8 == 0.
    // XCD k executes logical block ids [k*1024,(k+1)*1024) in issue order,
    // so blocks m and m+1 (sharing input row m+1) land on the same XCD.
    const int bid   = blockIdx.x;
    const int chunk = gridDim.x >> 3;            // 8192/8 = 1024
    const int lid   = (bid & 7) * chunk + (bid >> 3);

    const int np = threadIdx.x;                   // 0..255 column-pair
    const int m  = lid & 511;                     // input row
    const int b  = lid >> 9;                      // batch

    const int n0 = np << 1;
    const int n2 = (n0 + 2 < 512) ? n0 + 2 : 511; // clamp only at np==255
    const int mB = (m < 511) ? m + 1 : 511;       // symmetric-pad clamp

    const size_t rowA = ((size_t)(b << 9) + m) * 512;
    const size_t rowB = ((size_t)(b << 9) + mB) * 512;

    const float4 pA0 = x[rowA + n0], pA1 = x[rowA + n0 + 1], pA2 = x[rowA + n2];
    const float4 pB0 = x[rowB + n0], pB1 = x[rowB + n0 + 1], pB2 = x[rowB + n2];

    float Lv0[3], Lv1[3], Hv0[3], Hv1[3];
    {
        const float4 pa[3] = {pA0, pA1, pA2};
        const float4 pb[3] = {pB0, pB1, pB2};
#pragma unroll
        for (int j = 0; j < 3; ++j) {
            const float LA = pa[j].x + pa[j].y;
            const float LB = pb[j].x + pb[j].y;
            Lv0[j] = h2 * LA + h0 * LB;
            Lv1[j] = h3 * LA + h1 * LB;
            Hv0[j] = (h2 * pa[j].z + h0 * pb[j].z) + (h1 * pa[j].w + h3 * pb[j].w);
            Hv1[j] = (h3 * pa[j].z + h1 * pb[j].z) + (-h0 * pa[j].w - h2 * pb[j].w);
        }
    }

    // horizontal: lpf ec=0 (h2,h0), ec=1 (h3,h1); hpf ec=0 (h1,h3), ec=1 (-h0,-h2)
    nfloat4 r0, r1;
    r0.x = h2 * Lv0[0] + h0 * Lv0[1] + h1 * Hv0[0] + h3 * Hv0[1];
    r0.y = h3 * Lv0[0] + h1 * Lv0[1] - h0 * Hv0[0] - h2 * Hv0[1];
    r0.z = h2 * Lv0[1] + h0 * Lv0[2] + h1 * Hv0[1] + h3 * Hv0[2];
    r0.w = h3 * Lv0[1] + h1 * Lv0[2] - h0 * Hv0[1] - h2 * Hv0[2];
    r1.x = h2 * Lv1[0] + h0 * Lv1[1] + h1 * Hv1[0] + h3 * Hv1[1];
    r1.y = h3 * Lv1[0] + h1 * Lv1[1] - h0 * Hv1[0] - h2 * Hv1[1];
    r1.z = h2 * Lv1[1] + h0 * Lv1[2] + h1 * Hv1[1] + h3 * Hv1[2];
    r1.w = h3 * Lv1[1] + h1 * Lv1[2] - h0 * Hv1[1] - h2 * Hv1[2];

    // out: [B, 1024, 1024] fp32 = rows of 256 float4; this thread owns
    // output rows 2m, 2m+1, float4-col np. Non-temporal: write-once data,
    // keep it out of L2/L3 so the input stays cache-resident.
    const size_t o0 = ((size_t)(b << 10) + (m << 1)) * 256 + np;
    nfloat4* o = reinterpret_cast<nfloat4*>(out);
    __builtin_nontemporal_store(r0, o + o0);
    __builtin_nontemporal_store(r1, o + o0 + 256);
}

extern "C" void kernel_launch(void* const* d_in, const int* in_sizes, int n_in,
                              void* d_out, int out_size, void* d_ws, size_t ws_size,
                              hipStream_t stream) {
    const float4* x = (const float4*)d_in[0];
    float4* out = (float4*)d_out;
    // one thread per (b, m, column-pair): 32 * 512 * 256 threads
    const int blocks = 32 * 512 * 256 / 256;   // 8192, divisible by 8
    idwt_kernel<<<blocks, 256, 0, stream>>>(x, out);
}

// Round 6
// 223.727 us; speedup vs baseline: 1.1025x; 1.0265x over previous
//
#include <hip/hip_runtime.h>

// db2 coefficients (standard Daubechies-2, matches reference construction)
constexpr float h0 = 0.48296291314469025f;  // (1+√3)/(4√2)
constexpr float h1 = 0.83651630373746900f;  // (3+√3)/(4√2)
constexpr float h2 = 0.22414386804185735f;  // (3-√3)/(4√2)
constexpr float h3 = -0.12940952255092145f; // (1-√3)/(4√2)

// lpf = [h3,h2,h1,h0]; hpf = [-h0,h1,-h2,h3]
// Output row r = 2m+er taps orig rows m, min(m+1,511).
//   lpf vertical: er=0 -> (h2, h0); er=1 -> (h3, h1)
//   hpf vertical: er=0 -> (h1, h3); er=1 -> (-h0, -h2)
// Channels: c0,c1 = (lpf,lpf) [LH replicates source bug -> pre-summed];
// c2 = (lpf_h, hpf_w); c3 = (hpf_h, hpf_w); c2,c3 share horizontal hpf.
//
// V6: V1 shape (one thread = one row-pair x col-pair, 2M threads, TLP-max)
// + liveness pins on all 6 loads. V5b post-mortem: VGPR=24 proves the
// compiler split the 6 loads into >=2 vmcnt(0) groups -> serial chain
// ~2x600cy, not hideable at any occupancy (Little's law) -> 2.5 TB/s.
// Pinning all 6 float4 live at one point forces issue-6/drain-once
// (~800cy chain, coverable by 6-8 waves/SIMD). 24 data VGPRs + addr
// fits well under the 64-VGPR (8 waves/SIMD) boundary, unlike V2-V4's
// 60-reg body that the allocator refused.
// Dropped from V5b: XCD swizzle (input is L3-resident -- FETCH 65MB<134MB;
// swizzle costs ~2% when L3-fit) and NT stores (regressed vs V1).

#define PIN4(v) asm volatile("" :: "v"((v).x), "v"((v).y), "v"((v).z), "v"((v).w))

__global__ __launch_bounds__(256) void idwt_kernel(const float4* __restrict__ x,
                                                   float4* __restrict__ out) {
    const int idx = blockIdx.x * blockDim.x + threadIdx.x;
    const int np = idx & 255;        // column-pair index, 256 per row
    const int t = idx >> 8;
    const int m = t & 511;
    const int b = t >> 9;

    const int n0 = np << 1;
    const int n2 = (n0 + 2 < 512) ? n0 + 2 : 511;   // clamp only at np==255
    const int mB = (m < 511) ? m + 1 : 511;

    const size_t rowA = (size_t)((b << 9) + m) * 512;
    const size_t rowB = (size_t)((b << 9) + mB) * 512;

    // Issue all 6 loads, then pin every result live: forces a single
    // graduated vmcnt drain instead of two serialized load/consume groups.
    const float4 pA0 = x[rowA + n0], pA1 = x[rowA + n0 + 1], pA2 = x[rowA + n2];
    const float4 pB0 = x[rowB + n0], pB1 = x[rowB + n0 + 1], pB2 = x[rowB + n2];
    PIN4(pA0); PIN4(pA1); PIN4(pA2);
    PIN4(pB0); PIN4(pB1); PIN4(pB2);

    float Lv0[3], Lv1[3], Hv0[3], Hv1[3];
    {
        const float4 pa[3] = {pA0, pA1, pA2};
        const float4 pb[3] = {pB0, pB1, pB2};
#pragma unroll
        for (int j = 0; j < 3; ++j) {
            const float LA = pa[j].x + pa[j].y;
            const float LB = pb[j].x + pb[j].y;
            Lv0[j] = h2 * LA + h0 * LB;
            Lv1[j] = h3 * LA + h1 * LB;
            Hv0[j] = (h2 * pa[j].z + h0 * pb[j].z) + (h1 * pa[j].w + h3 * pb[j].w);
            Hv1[j] = (h3 * pa[j].z + h1 * pb[j].z) + (-h0 * pa[j].w - h2 * pb[j].w);
        }
    }

    // horizontal: lpf ec=0 (h2,h0), ec=1 (h3,h1); hpf ec=0 (h1,h3), ec=1 (-h0,-h2)
    float4 r0, r1;
    r0.x = h2 * Lv0[0] + h0 * Lv0[1] + h1 * Hv0[0] + h3 * Hv0[1];
    r0.y = h3 * Lv0[0] + h1 * Lv0[1] - h0 * Hv0[0] - h2 * Hv0[1];
    r0.z = h2 * Lv0[1] + h0 * Lv0[2] + h1 * Hv0[1] + h3 * Hv0[2];
    r0.w = h3 * Lv0[1] + h1 * Lv0[2] - h0 * Hv0[1] - h2 * Hv0[2];
    r1.x = h2 * Lv1[0] + h0 * Lv1[1] + h1 * Hv1[0] + h3 * Hv1[1];
    r1.y = h3 * Lv1[0] + h1 * Lv1[1] - h0 * Hv1[0] - h2 * Hv1[1];
    r1.z = h2 * Lv1[1] + h0 * Lv1[2] + h1 * Hv1[1] + h3 * Hv1[2];
    r1.w = h3 * Lv1[1] + h1 * Lv1[2] - h0 * Hv1[1] - h2 * Hv1[2];

    // out: [B, 1024, 1024] fp32 = rows of 256 float4; this thread owns
    // rows 2m, 2m+1, float4-col np.
    const size_t o0 = (size_t)((b << 10) + (m << 1)) * 256 + np;
    out[o0]       = r0;
    out[o0 + 256] = r1;
}

extern "C" void kernel_launch(void* const* d_in, const int* in_sizes, int n_in,
                              void* d_out, int out_size, void* d_ws, size_t ws_size,
                              hipStream_t stream) {
    const float4* x = (const float4*)d_in[0];
    float4* out = (float4*)d_out;
    const int total = 32 * 512 * 256;   // one thread per (b, m, column-pair)
    idwt_kernel<<<total / 256, 256, 0, stream>>>(x, out);
}